// Round 2
// baseline (272.122 us; speedup 1.0000x reference)
//
#include <hip/hip_runtime.h>
#include <math.h>

// TopKSoftMax: rows of D=64 f32; keep top-8 (ties -> lower index, exactly as
// jax.lax.top_k), softmax over kept, zeros elsewhere.
//
// R2: pure-register version. One thread per row; 16x global_load_dwordx4 per
// thread (256B lane stride - each 64B line fully consumed by one lane), row
// kept in VGPRs, no LDS, no barriers. ~90 VGPR -> 4 waves/SIMD (16 waves/CU),
// vs R1's LDS-capped 10 waves/CU with 3 barrier phases.

#define D       64
#define D4      16          // float4s per row
#define THREADS 256

// one level of the sorted-insert chain: ti = max(ti, a); a = min(ti_old, a)
#define LVL(ti) { const float _hi = fmaxf(ti, _a); _a = fminf(ti, _a); ti = _hi; }
// insert x into t0 >= t1 >= ... >= t7 (last level needs only max)
#define INSERT(x) { float _a = (x); \
    LVL(t0) LVL(t1) LVL(t2) LVL(t3) LVL(t4) LVL(t5) LVL(t6) \
    t7 = fmaxf(t7, _a); }

// keep if strictly > thr, or == thr while index-ordered quota remains
#define PROC(x, o) { \
    const int _kgt = ((x) > thr); \
    const int _keq = ((x) == thr) & (quota > 0); \
    quota -= _keq; \
    (o) = (_kgt | _keq) ? __expf((x) - m) * inv : 0.0f; }

__global__ __launch_bounds__(THREADS, 4)
void topk_softmax_kernel(const float* __restrict__ in,
                         float* __restrict__ out,
                         int nrows)
{
    const int row = blockIdx.x * THREADS + threadIdx.x;
    if (row >= nrows) return;

    const float4* __restrict__ p = reinterpret_cast<const float4*>(in) + (long long)row * D4;
    float4* __restrict__ q       = reinterpret_cast<float4*>(out)      + (long long)row * D4;

    // ---- load whole row into registers (16 x dwordx4, all issued up front) ----
    float4 v[D4];
    #pragma unroll
    for (int c = 0; c < D4; ++c) v[c] = p[c];

    // ---- pass 1: top-8 via 8-deep compare-swap chain ----
    float t0 = -INFINITY, t1 = -INFINITY, t2 = -INFINITY, t3 = -INFINITY,
          t4 = -INFINITY, t5 = -INFINITY, t6 = -INFINITY, t7 = -INFINITY;
    #pragma unroll
    for (int c = 0; c < D4; ++c) {
        INSERT(v[c].x) INSERT(v[c].y) INSERT(v[c].z) INSERT(v[c].w)
    }

    // thr = 8th order statistic; m = row max
    const float thr = t7;
    const float m   = t0;
    // elements strictly greater than thr are all inside {t0..t6}
    int quota = 8 - ((t0 > thr) + (t1 > thr) + (t2 > thr) + (t3 > thr) +
                     (t4 > thr) + (t5 > thr) + (t6 > thr));
    // kept multiset == {t0..t7}: denominator from registers (8 exps only)
    const float sum = __expf(t0 - m) + __expf(t1 - m) + __expf(t2 - m) + __expf(t3 - m) +
                      __expf(t4 - m) + __expf(t5 - m) + __expf(t6 - m) + __expf(t7 - m);
    const float inv = 1.0f / sum;

    // ---- pass 2: softmax from registers, store (index order for tie quota) ----
    #pragma unroll
    for (int c = 0; c < D4; ++c) {
        float4 o;
        PROC(v[c].x, o.x) PROC(v[c].y, o.y) PROC(v[c].z, o.z) PROC(v[c].w, o.w)
        q[c] = o;
    }
}

extern "C" void kernel_launch(void* const* d_in, const int* in_sizes, int n_in,
                              void* d_out, int out_size, void* d_ws, size_t ws_size,
                              hipStream_t stream) {
    const float* in = (const float*)d_in[0];
    float* out = (float*)d_out;
    const int nrows = in_sizes[0] / D;
    const int blocks = (nrows + THREADS - 1) / THREADS;
    topk_softmax_kernel<<<blocks, THREADS, 0, stream>>>(in, out, nrows);
}

// Round 3
// 113.193 us; speedup vs baseline: 2.4040x; 2.4040x over previous
//
#include <hip/hip_runtime.h>
#include <math.h>

// TopKSoftMax: rows of D=64 f32; keep top-8 (ties -> lower index, exactly as
// jax.lax.top_k), softmax over kept, zeros elsewhere.
//
// R3: register-resident rows + in-register 16x16 XOR transpose (ds_swizzle).
// - Loads/stores: 16x dwordx4 per lane, instruction-coalesced (1KB/inst/wave).
//   R2 showed scattered 16B/lane stores cause partial-line eviction: WRITE_SIZE
//   620MB vs 262MB ideal + RFO fetches. This keeps both sides fully coalesced.
// - Transpose: 4 butterfly stages (xor 1,2,4,8) swap lane bits 0-3 with reg
//   bits 0-3. After transpose lane j owns row 4*(j&15)+(j>>4), regs = colblocks
//   in order. Same involution maps outputs back to the coalesced store layout.
// - No LDS, no barriers; occupancy capped only by VGPRs (~96, bound to 128).

#define D       64
#define D4      16
#define THREADS 256
#define ROWS_PER_BLOCK 256   // 4 waves x 64 rows

#define SWZ(x, pat) __int_as_float(__builtin_amdgcn_ds_swizzle(__float_as_int(x), pat))

// one level of the sorted-insert chain: ti = max(ti, a); a = min(ti_old, a)
#define LVL(ti) { const float _hi = fmaxf(ti, _a); _a = fminf(ti, _a); ti = _hi; }
#define INSERT(x) { float _a = (x); \
    LVL(t0) LVL(t1) LVL(t2) LVL(t3) LVL(t4) LVL(t5) LVL(t6) \
    t7 = fmaxf(t7, _a); }

// keep if strictly > thr, or == thr while index-ordered quota remains
#define PROC(x, o) { \
    const int _kgt = ((x) > thr); \
    const int _keq = ((x) == thr) & (quota > 0); \
    quota -= _keq; \
    (o) = (_kgt | _keq) ? __expf((x) - m) * inv : 0.0f; }

template<int S>
__device__ __forceinline__ void xstage(float4 (&v)[D4], int lane) {
    constexpr int PAT = ((1 << S) << 10) | 0x1F;   // ds_swizzle BitMode: xor=1<<S, and=0x1F
    const bool hiL = (lane >> S) & 1;
    #pragma unroll
    for (int c0 = 0; c0 < D4; ++c0) {
        if (((c0 >> S) & 1) == 0) {
            const int c1 = c0 | (1 << S);
            float4 ta, tb;
            ta.x = SWZ(v[c1].x, PAT); ta.y = SWZ(v[c1].y, PAT);
            ta.z = SWZ(v[c1].z, PAT); ta.w = SWZ(v[c1].w, PAT);
            tb.x = SWZ(v[c0].x, PAT); tb.y = SWZ(v[c0].y, PAT);
            tb.z = SWZ(v[c0].z, PAT); tb.w = SWZ(v[c0].w, PAT);
            // lanes with bit S set take the partner's values for c0; others for c1
            v[c0].x = hiL ? ta.x : v[c0].x;  v[c0].y = hiL ? ta.y : v[c0].y;
            v[c0].z = hiL ? ta.z : v[c0].z;  v[c0].w = hiL ? ta.w : v[c0].w;
            v[c1].x = hiL ? v[c1].x : tb.x;  v[c1].y = hiL ? v[c1].y : tb.y;
            v[c1].z = hiL ? v[c1].z : tb.z;  v[c1].w = hiL ? v[c1].w : tb.w;
        }
    }
}

__device__ __forceinline__ void topk_softmax_row(float4 (&v)[D4]) {
    float t0 = -INFINITY, t1 = -INFINITY, t2 = -INFINITY, t3 = -INFINITY,
          t4 = -INFINITY, t5 = -INFINITY, t6 = -INFINITY, t7 = -INFINITY;
    #pragma unroll
    for (int c = 0; c < D4; ++c) {
        INSERT(v[c].x) INSERT(v[c].y) INSERT(v[c].z) INSERT(v[c].w)
    }
    const float thr = t7;            // 8th order statistic
    const float m   = t0;            // row max
    int quota = 8 - ((t0 > thr) + (t1 > thr) + (t2 > thr) + (t3 > thr) +
                     (t4 > thr) + (t5 > thr) + (t6 > thr));
    const float sum = __expf(t0 - m) + __expf(t1 - m) + __expf(t2 - m) + __expf(t3 - m) +
                      __expf(t4 - m) + __expf(t5 - m) + __expf(t6 - m) + __expf(t7 - m);
    const float inv = 1.0f / sum;
    #pragma unroll
    for (int c = 0; c < D4; ++c) {
        float4 o;
        PROC(v[c].x, o.x) PROC(v[c].y, o.y) PROC(v[c].z, o.z) PROC(v[c].w, o.w)
        v[c] = o;
    }
}

__global__ __launch_bounds__(THREADS, 4)
void topk_softmax_kernel(const float* __restrict__ in,
                         float* __restrict__ out,
                         int nrows)
{
    const int lane = threadIdx.x & 63;
    const int wid  = threadIdx.x >> 6;
    const long long block_row = (long long)blockIdx.x * ROWS_PER_BLOCK;

    if (block_row + ROWS_PER_BLOCK <= nrows) {
        // ---- fast path: whole block in range, all 64 lanes of each wave active ----
        const long long wave_row = block_row + wid * 64;
        const float4* __restrict__ p = reinterpret_cast<const float4*>(in) + wave_row * D4;
        float4* __restrict__ q       = reinterpret_cast<float4*>(out)      + wave_row * D4;

        float4 v[D4];
        #pragma unroll
        for (int c = 0; c < D4; ++c) v[c] = p[c * 64 + lane];   // coalesced: 1KB/inst

        xstage<0>(v, lane); xstage<1>(v, lane); xstage<2>(v, lane); xstage<3>(v, lane);

        topk_softmax_row(v);   // lane owns row 4*(lane&15)+(lane>>4) of this wave's 64

        xstage<0>(v, lane); xstage<1>(v, lane); xstage<2>(v, lane); xstage<3>(v, lane);

        #pragma unroll
        for (int c = 0; c < D4; ++c) q[c * 64 + lane] = v[c];   // coalesced: 1KB/inst
    } else {
        // ---- tail fallback (never taken for nrows % 256 == 0): row-per-thread ----
        const long long row = block_row + threadIdx.x;
        if (row >= nrows) return;
        const float4* __restrict__ p = reinterpret_cast<const float4*>(in) + row * D4;
        float4* __restrict__ q       = reinterpret_cast<float4*>(out)      + row * D4;
        float4 v[D4];
        #pragma unroll
        for (int c = 0; c < D4; ++c) v[c] = p[c];
        topk_softmax_row(v);
        #pragma unroll
        for (int c = 0; c < D4; ++c) q[c] = v[c];
    }
}

extern "C" void kernel_launch(void* const* d_in, const int* in_sizes, int n_in,
                              void* d_out, int out_size, void* d_ws, size_t ws_size,
                              hipStream_t stream) {
    const float* in = (const float*)d_in[0];
    float* out = (float*)d_out;
    const int nrows = in_sizes[0] / D;
    const int blocks = (nrows + ROWS_PER_BLOCK - 1) / ROWS_PER_BLOCK;
    topk_softmax_kernel<<<blocks, THREADS, 0, stream>>>(in, out, nrows);
}

// Round 4
// 108.592 us; speedup vs baseline: 2.5059x; 1.0424x over previous
//
#include <hip/hip_runtime.h>
#include <math.h>

// TopKSoftMax: rows of D=64 f32; keep top-8 (ties -> lower index, exactly as
// jax.lax.top_k), softmax over kept, zeros elsewhere.
//
// R4: LDS-transpose version (replaces R3's 512-swizzle in-register transpose,
// which co-limited with HBM on the LDS pipe).
//  - in:  16x global_load_lds_dwordx4, global source pre-swizzled (m173 trick)
//         so linear LDS dest = XOR-swizzled tile: slot(r,k) = r*16 + (k^(r&15))
//  - row: 16x ds_read_b128 (bank-uniform via the XOR swizzle)
//  - out: 16x ds_write_b128 + 16x coalesced ds_read_b128 + global_store_dwordx4
//  - per-wave private 16 KB tile, NO barriers (within-wave reuse: waitcnt only)
// 48 ds ops/wave (~580 cyc) vs R3's ~512 swizzles (~3000 cyc) on the LDS pipe.

#define D       64
#define D4      16
#define WAVES   2
#define THREADS (WAVES * 64)
#define ROWS_PER_BLOCK (WAVES * 64)

// one level of the sorted-insert chain: ti = max(ti, a); a = min(ti_old, a)
#define LVL(ti) { const float _hi = fmaxf(ti, _a); _a = fminf(ti, _a); ti = _hi; }
#define INSERT(x) { float _a = (x); \
    LVL(t0) LVL(t1) LVL(t2) LVL(t3) LVL(t4) LVL(t5) LVL(t6) \
    t7 = fmaxf(t7, _a); }

// keep if strictly > thr, or == thr while index-ordered quota remains
#define PROC(x, o) { \
    const int _kgt = ((x) > thr); \
    const int _keq = ((x) == thr) & (quota > 0); \
    quota -= _keq; \
    (o) = (_kgt | _keq) ? __expf((x) - m) * inv : 0.0f; }

__device__ __forceinline__ void gload_lds16(const void* g, void* l) {
    __builtin_amdgcn_global_load_lds(
        (__attribute__((address_space(1))) void*)(g),
        (__attribute__((address_space(3))) void*)(l),
        16, 0, 0);   // 16B/lane -> global_load_lds_dwordx4
}

__device__ __forceinline__ void topk_softmax_row(float4 (&v)[D4]) {
    float t0 = -INFINITY, t1 = -INFINITY, t2 = -INFINITY, t3 = -INFINITY,
          t4 = -INFINITY, t5 = -INFINITY, t6 = -INFINITY, t7 = -INFINITY;
    #pragma unroll
    for (int c = 0; c < D4; ++c) {
        INSERT(v[c].x) INSERT(v[c].y) INSERT(v[c].z) INSERT(v[c].w)
    }
    const float thr = t7;            // 8th order statistic
    const float m   = t0;            // row max
    int quota = 8 - ((t0 > thr) + (t1 > thr) + (t2 > thr) + (t3 > thr) +
                     (t4 > thr) + (t5 > thr) + (t6 > thr));
    const float sum = __expf(t0 - m) + __expf(t1 - m) + __expf(t2 - m) + __expf(t3 - m) +
                      __expf(t4 - m) + __expf(t5 - m) + __expf(t6 - m) + __expf(t7 - m);
    const float inv = 1.0f / sum;
    #pragma unroll
    for (int c = 0; c < D4; ++c) {
        float4 o;
        PROC(v[c].x, o.x) PROC(v[c].y, o.y) PROC(v[c].z, o.z) PROC(v[c].w, o.w)
        v[c] = o;
    }
}

__global__ __launch_bounds__(THREADS)
void topk_softmax_kernel(const float* __restrict__ in,
                         float* __restrict__ out,
                         int nrows)
{
    __shared__ float4 tile[WAVES][64 * D4];   // 16 KB per wave, private

    const int lane = threadIdx.x & 63;
    const int wid  = threadIdx.x >> 6;
    const long long block_row = (long long)blockIdx.x * ROWS_PER_BLOCK;

    if (block_row + ROWS_PER_BLOCK <= nrows) {
        const long long wave_row = block_row + (long long)wid * 64;
        const float4* __restrict__ p = reinterpret_cast<const float4*>(in) + wave_row * D4;
        float4* __restrict__ q       = reinterpret_cast<float4*>(out)      + wave_row * D4;
        float4* t = tile[wid];

        // ---- global -> LDS: coalesced 1KB/inst, source pre-swizzled so that
        //      LDS slot r*16 + (k ^ (r&15)) receives (row r, float4 k) ----
        #pragma unroll
        for (int c = 0; c < D4; ++c) {
            const int r = c * 4 + (lane >> 4);              // row of linear slot
            const int k = (lane & 15) ^ (r & 15);           // float4 to fetch
            gload_lds16(p + r * 16 + k, t + c * 64);        // dst wave-uniform
        }
        asm volatile("s_waitcnt vmcnt(0)" ::: "memory");

        // ---- own row -> regs (bank-uniform b128 reads) ----
        const int swz = lane & 15;
        float4 v[D4];
        #pragma unroll
        for (int c = 0; c < D4; ++c) v[c] = t[lane * 16 + (c ^ swz)];

        topk_softmax_row(v);

        // ---- results back to same swizzled slots ----
        #pragma unroll
        for (int c = 0; c < D4; ++c) t[lane * 16 + (c ^ swz)] = v[c];
        asm volatile("s_waitcnt lgkmcnt(0)" ::: "memory");  // cross-lane, same wave

        // ---- coalesced out: slot holding flat element (c*64 + lane) ----
        #pragma unroll
        for (int c = 0; c < D4; ++c) {
            const int r = c * 4 + (lane >> 4);
            const int s = lane & 15;
            q[c * 64 + lane] = t[r * 16 + (s ^ (r & 15))];
        }
    } else {
        // ---- tail fallback (not taken for nrows % 128 == 0) ----
        const long long row = block_row + threadIdx.x;
        if (row >= nrows) return;
        const float4* __restrict__ p = reinterpret_cast<const float4*>(in) + row * D4;
        float4* __restrict__ q       = reinterpret_cast<float4*>(out)      + row * D4;
        float4 v[D4];
        #pragma unroll
        for (int c = 0; c < D4; ++c) v[c] = p[c];
        topk_softmax_row(v);
        #pragma unroll
        for (int c = 0; c < D4; ++c) q[c] = v[c];
    }
}

extern "C" void kernel_launch(void* const* d_in, const int* in_sizes, int n_in,
                              void* d_out, int out_size, void* d_ws, size_t ws_size,
                              hipStream_t stream) {
    const float* in = (const float*)d_in[0];
    float* out = (float*)d_out;
    const int nrows = in_sizes[0] / D;
    const int blocks = (nrows + ROWS_PER_BLOCK - 1) / ROWS_PER_BLOCK;
    topk_softmax_kernel<<<blocks, THREADS, 0, stream>>>(in, out, nrows);
}